// Round 3
// baseline (724.337 us; speedup 1.0000x reference)
//
#include <hip/hip_runtime.h>

typedef unsigned char u8;

#define TT 1024
#define BB 512
#define LL 50
#define STOPI 48
#define STARTI 49
#define NEGV -10000.0f
#define NINF -3.4e38f

// raw barrier: waits own LDS ops only, does NOT drain vmcnt (global prefetch
// loads stay in flight). "memory" clobber stops compiler reordering LDS ops.
#define WAVE_BARRIER() asm volatile("s_waitcnt lgkmcnt(0)\n\ts_barrier" ::: "memory")

// ws layout:
//   [0, 2048)             : int idx[512]
//   [4096, 4096+B*50*T)   : u8 ptr[B][50][T]  backpointers, [label][time]

// 4 waves per batch, from-split 13/13/13/11. One raw barrier per step.
// Every wave redundantly combines partials -> holds full replicated vit, so
// each wave readlanes only its own from-range. Partials parity double-buffered.
__global__ __launch_bounds__(256) void viterbi_fwd(
    const float* __restrict__ feats, const int* __restrict__ lens,
    const float* __restrict__ trans, float* __restrict__ out_scores,
    int* __restrict__ idx_ws, u8* __restrict__ ptr_ws)
{
    const int b    = blockIdx.x;
    const int tid  = threadIdx.x;
    const int lane = tid & 63;            // lane == 'to' label
    const int q    = tid >> 6;            // wave id: from-range owner
    const int row  = (lane < LL) ? lane : (LL - 1);
    const int fstart = q * 13;            // q0:0..12 q1:13..25 q2:26..38 q3:39..49
    const int cnt    = (q == 3) ? 11 : 13;

    // transitions for (to=lane, from in my range) -> registers
    float trr[13];
#pragma unroll
    for (int j = 0; j < 13; ++j) {
        int jj = (j < cnt) ? j : 0;
        trr[j] = trans[row * LL + fstart + jj];
    }
    const float tr_stop = trans[STOPI * LL + row];

    const int len = lens[b];
    const int nchunks = (len + 15) >> 4;

    float vit = (lane == STARTI) ? 0.0f : NEGV;   // replicated in all 4 waves

    __shared__ float featbuf[2][1024];   // 16 rows x 50, padded
    __shared__ float pb[2][4][64];       // partial best  [parity][q][to]
    __shared__ int   pi[2][4][64];       // partial index [parity][q][to]

    const float* fb = feats + (size_t)b * (TT * LL);
    u8* pt = ptr_ws + (size_t)b * (TT * LL) + (size_t)row * TT;

    // stage chunk 0, prefetch chunk 1 (200 float4 = 800 floats per chunk)
    float4 pf;
    if (tid < 200) {
        pf = *(const float4*)(fb + tid * 4);
        ((float4*)featbuf[0])[tid] = pf;
        pf = *(const float4*)(fb + 800 + tid * 4);   // chunk 1 (clamp n/a: 1<=63)
    }
    WAVE_BARRIER();

    // tournament node: b wins only if strictly greater -> lower index keeps ties
#define NODE(AV, AI, BV, BI) { if ((BV) > (AV)) { (AV) = (BV); (AI) = (BI); } }

    // partial over my 13-from range -> (bestv, besti); first-index exact
#define PARTIAL(BESTV, BESTI)                                                  \
    {                                                                          \
        float bv[13]; int bi[13];                                              \
        _Pragma("unroll")                                                      \
        for (int j = 0; j < 13; ++j) {                                         \
            int jj = (j < cnt) ? j : 0;                                        \
            float s = __int_as_float(                                          \
                __builtin_amdgcn_readlane(__float_as_int(vit), fstart + jj))   \
                + trr[j];                                                      \
            bv[j] = (j < cnt) ? s : NINF;                                      \
            bi[j] = fstart + j;                                                \
        }                                                                      \
        NODE(bv[0], bi[0], bv[1], bi[1])  NODE(bv[2], bi[2], bv[3], bi[3])     \
        NODE(bv[4], bi[4], bv[5], bi[5])  NODE(bv[6], bi[6], bv[7], bi[7])     \
        NODE(bv[8], bi[8], bv[9], bi[9])  NODE(bv[10],bi[10],bv[11],bi[11])    \
        NODE(bv[0], bi[0], bv[2], bi[2])  NODE(bv[4], bi[4], bv[6], bi[6])     \
        NODE(bv[8], bi[8], bv[10],bi[10])                                      \
        NODE(bv[0], bi[0], bv[4], bi[4])  NODE(bv[8], bi[8], bv[12],bi[12])    \
        NODE(bv[0], bi[0], bv[8], bi[8])                                       \
        (BESTV) = bv[0]; (BESTI) = bi[0];                                      \
    }

    unsigned pk = 0;
    for (int c = 0; c < nchunks; ++c) {
        const int p = c & 1;
        // stage chunk c+1 into the other buffer; prefetch chunk c+2
        if (tid < 200) {
            ((float4*)featbuf[1 - p])[tid] = pf;
            int c2 = c + 2; if (c2 > 63) c2 = 63;
            pf = *(const float4*)(fb + c2 * 800 + tid * 4);
        }
        for (int i = 0; i < 16; ++i) {
            const int t = (c << 4) + i;
            const float f = featbuf[p][i * 50 + lane];

            float bestv; int besti;
            PARTIAL(bestv, besti)
            pb[p][q][lane] = bestv;
            pi[p][q][lane] = besti;
            WAVE_BARRIER();

            float B = pb[p][0][lane]; int I = pi[p][0][lane];
            { float B1 = pb[p][1][lane]; int I1 = pi[p][1][lane]; NODE(B, I, B1, I1) }
            { float B2 = pb[p][2][lane]; int I2 = pi[p][2][lane]; NODE(B, I, B2, I2) }
            { float B3 = pb[p][3][lane]; int I3 = pi[p][3][lane]; NODE(B, I, B3, I3) }

            pk = (pk >> 8) | ((unsigned)I << 24);
            if (q == 0 && (t & 3) == 3 && lane < LL)
                *(unsigned*)(pt + t - 3) = pk;      // fire-and-forget

            if (t < len) {                          // uniform branch
                float nv = B + f;
                if (t == len - 1) nv += tr_stop;
                vit = nv;                           // identical in all 4 waves
            }
        }
    }

    // frozen row for t >= nchunks*16 (vit frozen)
    {
        const int p = nchunks & 1;
        float bestv; int besti;
        PARTIAL(bestv, besti)
        pb[p][q][lane] = bestv;
        pi[p][q][lane] = besti;
        WAVE_BARRIER();
        float B = pb[p][0][lane]; int I = pi[p][0][lane];
        { float B1 = pb[p][1][lane]; int I1 = pi[p][1][lane]; NODE(B, I, B1, I1) }
        { float B2 = pb[p][2][lane]; int I2 = pi[p][2][lane]; NODE(B, I, B2, I2) }
        { float B3 = pb[p][3][lane]; int I3 = pi[p][3][lane]; NODE(B, I, B3, I3) }

        const unsigned pat = (unsigned)I * 0x01010101u;
        uint4 qv; qv.x = pat; qv.y = pat; qv.z = pat; qv.w = pat;
        if (lane < LL)
            for (int c2 = nchunks + q; c2 < 64; c2 += 4)   // waves split the fill
                *(uint4*)(pt + (c2 << 4)) = qv;
    }

    // final score / first-index argmax over vit[0..49] (wave 0 only)
    if (q == 0) {
        float m = NINF; int mi = 0;
#pragma unroll
        for (int j = 0; j < LL; ++j) {
            float s = __int_as_float(__builtin_amdgcn_readlane(__float_as_int(vit), j));
            if (s > m) { m = s; mi = j; }
        }
        if (lane == 0) { out_scores[b] = m; idx_ws[b] = mi; }
    }
#undef PARTIAL
#undef NODE
}

// Backtrack with chunked pointer-jumping: 32 chunks x 32 steps.
// ptr layout transposed: lptr[label*1024 + t].
__global__ __launch_bounds__(64) void viterbi_bwd(
    const int* __restrict__ idx_ws, const u8* __restrict__ ptr_ws,
    float* __restrict__ out_paths)
{
    const int b = blockIdx.x;
    const int lane = threadIdx.x;

    __shared__ u8 lptr[TT * LL];
    __shared__ u8 maps[32 * LL];
    __shared__ int entries[33];

    {
        const uint4* src = (const uint4*)(ptr_ws + (size_t)b * TT * LL);
        uint4* dst = (uint4*)lptr;
        for (int i = lane; i < (TT * LL) / 16; i += 64) dst[i] = src[i];
    }
    __syncthreads();

    {
        int st[25], tt[25], cidx[25];
#pragma unroll
        for (int k = 0; k < 25; ++k) {
            int w = k * 64 + lane;
            int c = w / 50;
            int l = w - c * 50;
            st[k] = l;
            tt[k] = c * 32 + 31;
            cidx[k] = c * 50 + l;
        }
        for (int j = 0; j < 32; ++j) {
#pragma unroll
            for (int k = 0; k < 25; ++k) {
                st[k] = lptr[(st[k] << 10) + tt[k]];
                tt[k] -= 1;
            }
        }
#pragma unroll
        for (int k = 0; k < 25; ++k) maps[cidx[k]] = (u8)st[k];
    }
    __syncthreads();

    const int idx = idx_ws[b];

    if (lane == 0) {
        int i = idx;
        for (int c = 31; c >= 0; --c) {
            entries[c + 1] = i;
            i = maps[c * 50 + i];
        }
        entries[0] = i;
    }
    __syncthreads();

    float* po = out_paths + (size_t)b * TT;
    if (lane < 32) {
        const int c = lane;
        int s = entries[c + 1];
        for (int j = 0; j < 32; ++j) {
            int t = c * 32 + 31 - j;
            int ni = lptr[(s << 10) + t];
            if (t > 0) po[t - 1] = (float)ni;
            s = ni;
        }
    }
    if (lane == 0) po[TT - 1] = (float)idx;
}

extern "C" void kernel_launch(void* const* d_in, const int* in_sizes, int n_in,
                              void* d_out, int out_size, void* d_ws, size_t ws_size,
                              hipStream_t stream) {
    const float* feats = (const float*)d_in[0];
    const int*   lens  = (const int*)d_in[1];
    const float* trans = (const float*)d_in[2];

    float* scores = (float*)d_out;          // [512]
    float* paths  = scores + BB;            // [512*1024] ints as floats

    int* idx_ws = (int*)d_ws;
    u8*  ptr_ws = (u8*)d_ws + 4096;

    viterbi_fwd<<<BB, 256, 0, stream>>>(feats, lens, trans, scores, idx_ws, ptr_ws);
    viterbi_bwd<<<BB, 64, 0, stream>>>(idx_ws, ptr_ws, paths);
}